// Round 2
// baseline (146.779 us; speedup 1.0000x reference)
//
#include <hip/hip_runtime.h>
#include <hip/hip_bf16.h>

#define NSLOPE 0.2f

typedef __bf16 bf16x8 __attribute__((ext_vector_type(8)));
typedef float  f32x4  __attribute__((ext_vector_type(4)));

__device__ __forceinline__ float lrelu(float x) { return x >= 0.f ? x : NSLOPE * x; }

// -------- kernel 1: h_prime = h @ w, src/dst projections, write hp^T as bf16 --------
// grid: 32 bh * 32 ntiles ; block 256
__global__ __launch_bounds__(256) void k_hprime(
    const float* __restrict__ hg,     // [8,2048,64]
    const float* __restrict__ wg,     // [4,64,32]
    const float* __restrict__ a_src,  // [4,32]
    const float* __restrict__ a_dst,  // [4,32]
    __hip_bfloat16* __restrict__ hpT, // [32][32][2048]  (bh, o, n)
    float* __restrict__ srcv,         // [32][2048]
    float* __restrict__ dstv)         // [32][2048]
{
    __shared__ float w_lds[64 * 32];            // [f][o]
    __shared__ float h_lds[64 * 64];            // [nl][f]
    __shared__ __hip_bfloat16 t_lds[32 * 72];   // [o][nl] padded row=72

    const int t  = threadIdx.x;
    const int bh = blockIdx.x >> 5;
    const int n0 = (blockIdx.x & 31) * 64;
    const int b  = bh >> 2, hh = bh & 3;

    {
        const float4* s4 = (const float4*)(wg + hh * 2048);
        float4* d4 = (float4*)w_lds;
        d4[t] = s4[t];
        d4[t + 256] = s4[t + 256];
        const float4* s4h = (const float4*)(hg + ((size_t)(b * 2048 + n0)) * 64);
        float4* d4h = (float4*)h_lds;
#pragma unroll
        for (int k = 0; k < 4; k++) d4h[t + 256 * k] = s4h[t + 256 * k];
    }
    __syncthreads();

    const int o  = t & 31;
    const int nb = t >> 5;   // 0..7
    float acc[8];
#pragma unroll
    for (int k = 0; k < 8; k++) acc[k] = 0.f;
    for (int f = 0; f < 64; f++) {
        const float wv = w_lds[f * 32 + o];
#pragma unroll
        for (int k = 0; k < 8; k++)
            acc[k] = fmaf(h_lds[(nb + 8 * k) * 64 + f], wv, acc[k]);
    }
    const float as = a_src[hh * 32 + o];
    const float ad = a_dst[hh * 32 + o];
#pragma unroll
    for (int k = 0; k < 8; k++) {
        float sv = acc[k] * as;
        float dv = acc[k] * ad;
#pragma unroll
        for (int m = 16; m >= 1; m >>= 1) {
            sv += __shfl_xor(sv, m);
            dv += __shfl_xor(dv, m);
        }
        if (o == 0) {
            const int n = n0 + nb + 8 * k;
            srcv[bh * 2048 + n] = sv;
            dstv[bh * 2048 + n] = dv;
        }
    }
#pragma unroll
    for (int k = 0; k < 8; k++)
        t_lds[o * 72 + nb + 8 * k] = __float2bfloat16(acc[k]);
    __syncthreads();
    {
        const int oo = t >> 3;   // 0..31
        const int ch = t & 7;    // 8 n each
        const uint4 v = *(const uint4*)(&t_lds[oo * 72 + ch * 8]);
        *(uint4*)(hpT + ((size_t)(bh * 32 + oo)) * 2048 + n0 + ch * 8) = v;
    }
}

// -------- kernel 2: fused scores -> softmax -> attn write + MFMA PV --------
// grid: 32 bh * 32 rowtiles(64 rows) ; block 256 (4 waves, 16 rows/wave)
__global__ __launch_bounds__(256) void k_attn(
    const __hip_bfloat16* __restrict__ hpT,
    const float* __restrict__ srcv,
    const float* __restrict__ dstv,
    const float* __restrict__ bias,
    float* __restrict__ outp,   // [32][2048][32]
    float* __restrict__ attn)   // [32][2048][2048]
{
    __shared__ float dst_lds[2048];
    __shared__ float src_lds[64];
    __shared__ float m_lds[64];
    __shared__ float is_lds[64];
    __shared__ float red_lds[4];
    __shared__ char  hp_lds[8192];    // [32 rows][16 slots][16B], frag-permuted + swizzled
    __shared__ char  p_lds[16384];    // [64 rows][16 slots][16B], frag-permuted + swizzled

    const int t    = threadIdx.x;
    const int bh   = blockIdx.x >> 5;
    const int row0 = (blockIdx.x & 31) * 64;

    // stage dst[2048] + track max
    float lmax = -1e30f;
    {
        const float4* s4 = (const float4*)(dstv + bh * 2048);
        float4* d4 = (float4*)dst_lds;
#pragma unroll
        for (int k = 0; k < 2; k++) {
            const float4 v = s4[t + 256 * k];
            d4[t + 256 * k] = v;
            lmax = fmaxf(lmax, fmaxf(fmaxf(v.x, v.y), fmaxf(v.z, v.w)));
        }
    }
    if (t < 64) src_lds[t] = srcv[bh * 2048 + row0 + t];
#pragma unroll
    for (int m = 32; m >= 1; m >>= 1) lmax = fmaxf(lmax, __shfl_xor(lmax, m));
    if ((t & 63) == 0) red_lds[t >> 6] = lmax;
    __syncthreads();
    const float dmax = fmaxf(fmaxf(red_lds[0], red_lds[1]), fmaxf(red_lds[2], red_lds[3]));

    // prepass: per-row max (closed form, lrelu monotone) and inverse denominator
    {
        const int r = t >> 2, q = t & 3;
        const float sr  = src_lds[r];
        const float m_r = lrelu(sr + dmax);
        float s = 0.f;
        for (int it = 0; it < 128; it++) {
            const float4 dv = *(const float4*)(dst_lds + q * 4 + 16 * it);
            s += __expf(lrelu(sr + dv.x) - m_r);
            s += __expf(lrelu(sr + dv.y) - m_r);
            s += __expf(lrelu(sr + dv.z) - m_r);
            s += __expf(lrelu(sr + dv.w) - m_r);
        }
        s += __shfl_xor(s, 1);
        s += __shfl_xor(s, 2);
        if (q == 0) { m_lds[r] = m_r; is_lds[r] = 1.f / s; }
    }
    __syncthreads();

    f32x4 acc0 = {0.f, 0.f, 0.f, 0.f};
    f32x4 acc1 = {0.f, 0.f, 0.f, 0.f};
    const int wv_ = t >> 6;   // wave id
    const int l   = t & 63;
    const int lr  = l & 15;   // A-row-in-16 / B-col(o)
    const int g   = l >> 4;   // k-group

    for (int tile = 0; tile < 16; tile++) {
        const int j0 = tile * 128;
        // stage hp^T tile into LDS (fragment-permuted + XOR slot swizzle)
#pragma unroll
        for (int k = 0; k < 2; k++) {
            const int c    = t + 256 * k;   // 512 chunks of 16B
            const int oo   = c >> 4;
            const int slot = c & 15;
            const uint4 v = *(const uint4*)(hpT + ((size_t)(bh * 32 + oo)) * 2048 + j0 + slot * 8);
            const int jl = slot * 8;
            const int j5 = jl >> 5, jj = jl & 31;
            const int pos = ((jj & 12) << 1) + ((jj & 16) >> 2);  // jj&3==0 here
            char* base = hp_lds + oo * 256;
            const int sa1 = (j5 * 4 + (pos >> 3)) ^ (oo & 15);
            const int bi1 = (pos & 7) * 2;
            const int pos2 = pos + 8;
            const int sa2 = (j5 * 4 + (pos2 >> 3)) ^ (oo & 15);
            const int bi2 = (pos2 & 7) * 2;
            const unsigned long long lo = ((unsigned long long)v.y << 32) | (unsigned long long)v.x;
            const unsigned long long hi = ((unsigned long long)v.w << 32) | (unsigned long long)v.z;
            *(unsigned long long*)(base + (sa1 << 4) + bi1) = lo;
            *(unsigned long long*)(base + (sa2 << 4) + bi2) = hi;
        }
        // phase A: p = exp(lrelu(src+dst)-m)/s ; write attn f32 + p bf16 into LDS
        {
            const int jl = (t & 31) * 4;
            const int rB = (t >> 5) * 8;
            const int j5 = jl >> 5, jj = jl & 31;
            const int pos = ((jj & 12) << 1) + (jj & 3) + ((jj & 16) >> 2);
            const int sa = j5 * 4 + (pos >> 3);
            const int bi = (pos & 7) * 2;
            const float4 dj = *(const float4*)(dst_lds + j0 + jl);
#pragma unroll
            for (int k = 0; k < 8; k++) {
                const int r = rB + k;
                const float sr   = src_lds[r];
                const float m_r  = m_lds[r];
                const float is_r = is_lds[r];
                f32x4 p;
                p[0] = __expf(lrelu(sr + dj.x) - m_r) * is_r;
                p[1] = __expf(lrelu(sr + dj.y) - m_r) * is_r;
                p[2] = __expf(lrelu(sr + dj.z) - m_r) * is_r;
                p[3] = __expf(lrelu(sr + dj.w) - m_r) * is_r;
                __builtin_nontemporal_store(p,
                    (f32x4*)(attn + ((size_t)(bh * 2048) + row0 + r) * 2048 + j0 + jl));
                union { __hip_bfloat16 hb[4]; unsigned long long u; } pk;
                pk.hb[0] = __float2bfloat16(p[0]);
                pk.hb[1] = __float2bfloat16(p[1]);
                pk.hb[2] = __float2bfloat16(p[2]);
                pk.hb[3] = __float2bfloat16(p[3]);
                *(unsigned long long*)(p_lds + r * 256 + ((sa ^ (r & 15)) << 4) + bi) = pk.u;
            }
        }
        __syncthreads();
        // phase B: wave w owns rows 16w..16w+15 ; accumulate PV via MFMA 16x16x32 bf16
        {
            const char* prow  = p_lds + (wv_ * 16 + lr) * 256;
            const char* hrow0 = hp_lds + lr * 256;
            const char* hrow1 = hp_lds + (16 + lr) * 256;
#pragma unroll
            for (int ks = 0; ks < 4; ks++) {
                const int sidx = (((ks * 4 + g) ^ lr) << 4);
                const bf16x8 a  = *(const bf16x8*)(prow + sidx);
                const bf16x8 b0 = *(const bf16x8*)(hrow0 + sidx);
                const bf16x8 b1 = *(const bf16x8*)(hrow1 + sidx);
                acc0 = __builtin_amdgcn_mfma_f32_16x16x32_bf16(a, b0, acc0, 0, 0, 0);
                acc1 = __builtin_amdgcn_mfma_f32_16x16x32_bf16(a, b1, acc1, 0, 0, 0);
            }
        }
        __syncthreads();
    }
    // epilogue: C/D layout col=lane&15, row=(lane>>4)*4+reg
    {
        const float b0 = bias[lr];
        const float b1 = bias[16 + lr];
#pragma unroll
        for (int reg = 0; reg < 4; reg++) {
            const int grow = row0 + wv_ * 16 + g * 4 + reg;
            float* op = outp + ((size_t)(bh * 2048) + grow) * 32;
            op[lr]      = acc0[reg] + b0;
            op[16 + lr] = acc1[reg] + b1;
        }
    }
}

extern "C" void kernel_launch(void* const* d_in, const int* in_sizes, int n_in,
                              void* d_out, int out_size, void* d_ws, size_t ws_size,
                              hipStream_t stream) {
    (void)in_sizes; (void)n_in; (void)out_size; (void)ws_size;
    const float* h     = (const float*)d_in[0];
    const float* w     = (const float*)d_in[1];
    const float* a_src = (const float*)d_in[2];
    const float* a_dst = (const float*)d_in[3];
    const float* b     = (const float*)d_in[4];

    float* out  = (float*)d_out;
    float* attn = out + (size_t)8 * 4 * 2048 * 32;   // output first, then attn

    __hip_bfloat16* hpT = (__hip_bfloat16*)d_ws;                         // 4 MB
    float* srcv = (float*)((char*)d_ws + (size_t)32 * 32 * 2048 * 2);    // 256 KB
    float* dstv = srcv + 32 * 2048;                                      // 256 KB

    k_hprime<<<1024, 256, 0, stream>>>(h, w, a_src, a_dst, hpT, srcv, dstv);
    k_attn  <<<1024, 256, 0, stream>>>(hpT, srcv, dstv, b, out, attn);
}